// Round 8
// baseline (209.894 us; speedup 1.0000x reference)
//
#include <hip/hip_runtime.h>
#include <hip/hip_bf16.h>

#define M_DIM 16384
#define IN_DIM 512
#define H_DIM 1024
#define BH (M_DIM * H_DIM)
#define K2 1536                            // fused K for cand: 512 (x) + 1024 (rh)

typedef float f32x4 __attribute__((ext_vector_type(4)));
typedef short bf16x8 __attribute__((ext_vector_type(8)));

// ---------------- bf16 helpers ----------------
static __device__ __forceinline__ unsigned short f2bf(float f) {
    union { float f; unsigned u; } a; a.f = f;
    unsigned r = a.u + 0x7fffu + ((a.u >> 16) & 1u);  // RNE
    return (unsigned short)(r >> 16);
}
static __device__ __forceinline__ float bf2f(unsigned short u) {
    union { unsigned u; float f; } a; a.u = (unsigned)u << 16;
    return a.f;
}

// ===================================================================
// ws layout (bf16 elements), total 124.78 MB
// ===================================================================
#define OFF_HB   0u                        // 16384x1024
#define OFF_A2   16777216u                 // 16384x1536: cols 0-511 = x, 512-1535 = rh
#define OFF_WU   41943040u                 // 1024x1024
#define OFF_WR   42991616u                 // 1024x1024
#define OFF_W2   44040192u                 // 1024x1536: cols 0-511 = W_hx, 512-1535 = W_hh
#define OFF_U16  45613056u                 // 16384x1024
#define WS2_ELEMS 62390272u
#define WS2_NEED_BYTES (WS2_ELEMS * 2ull)

// One-pass fp32 -> bf16 conversion of all operands into the fused layout.
__global__ __launch_bounds__(256) void k_conv(const float* __restrict__ x,
                                              const float* __restrict__ h,
                                              const float* __restrict__ wu,
                                              const float* __restrict__ whx,
                                              const float* __restrict__ whh,
                                              const float* __restrict__ wr,
                                              unsigned short* __restrict__ ws) {
    const int total = 3604480;  // total 8-elem units
    for (int u = blockIdx.x * blockDim.x + threadIdx.x; u < total;
         u += gridDim.x * blockDim.x) {
        const float* src; unsigned short* d; int lu;
        if (u < 2097152)      { lu = u;
                                src = h + (size_t)lu * 8;
                                d = ws + OFF_HB + (size_t)lu * 8; }
        else if (u < 3145728) { lu = u - 2097152;                       // x -> A2 strided
                                src = x + (size_t)lu * 8;
                                d = ws + OFF_A2 + (size_t)(lu >> 6) * K2 + (lu & 63) * 8; }
        else if (u < 3276800) { lu = u - 3145728;
                                src = wu + (size_t)lu * 8;
                                d = ws + OFF_WU + (size_t)lu * 8; }
        else if (u < 3342336) { lu = u - 3276800;                       // whx -> W2 strided
                                src = whx + (size_t)lu * 8;
                                d = ws + OFF_W2 + (size_t)(lu >> 6) * K2 + (lu & 63) * 8; }
        else if (u < 3473408) { lu = u - 3342336;                       // whh -> W2 + 512
                                src = whh + (size_t)lu * 8;
                                d = ws + OFF_W2 + (size_t)(lu >> 7) * K2 + 512 + (lu & 127) * 8; }
        else                  { lu = u - 3473408;
                                src = wr + (size_t)lu * 8;
                                d = ws + OFF_WR + (size_t)lu * 8; }
        float4 a = *reinterpret_cast<const float4*>(src);
        float4 b = *reinterpret_cast<const float4*>(src + 4);
        uint4 p;
        p.x = (unsigned)f2bf(a.x) | ((unsigned)f2bf(a.y) << 16);
        p.y = (unsigned)f2bf(a.z) | ((unsigned)f2bf(a.w) << 16);
        p.z = (unsigned)f2bf(b.x) | ((unsigned)f2bf(b.y) << 16);
        p.w = (unsigned)f2bf(b.z) | ((unsigned)f2bf(b.w) << 16);
        *reinterpret_cast<uint4*>(d) = p;
    }
}

// ===================================================================
// Counted-vmcnt pipelined GEMM: BM=256 x BN=128, BK=64, 512 thr (8 waves 4x2),
// 3-slot LDS rotation. Slot = A[256][64] + B[128][64] = 24576 elems (48 KB).
// ===================================================================
#define SLOT_E 24576

// Stage one 128x64 half-tile (16 KB) via global_load_lds w=16, 512 threads,
// 2 loads/thread (= 2 vmcnt units/wave). Involution kc ^ (r&7) on global side.
static __device__ __forceinline__ void stage_half512(const unsigned short* __restrict__ src,
                                                     int rowBase, int ld, int ks,
                                                     unsigned short* lds, int tid) {
#pragma unroll
    for (int i = 0; i < 2; ++i) {
        int c = i * 512 + tid;            // chunk id in [0,1024): 128 rows x 8 chunks
        int r = c >> 3, kc = c & 7;
        int gc = kc ^ (r & 7);
        const unsigned short* g = src + (size_t)(rowBase + r) * ld + ks + gc * 8;
        __builtin_amdgcn_global_load_lds((const __attribute__((address_space(1))) void*)g,
                                         (__attribute__((address_space(3))) void*)(lds + c * 8),
                                         16, 0, 0);
    }
}

// Core pipelined loop. acc[4][4]: per-wave 64x64 output (4 m-frags x 4 n-frags).
// Per tile: 4 phases (one m-frag each: 8 MFMA). Stage units of tile t+2 at
// phases 0-2. Tail: vmcnt(6) (tile t+1 retired, t+2 in flight) + barrier.
template <int NT>
static __device__ __forceinline__ void gemm_pipe(const unsigned short* __restrict__ A, int aLd,
                                                 const unsigned short* __restrict__ B, int bLd,
                                                 int bm, int bn, unsigned short* L,
                                                 int tid, int wm, int wn, int frow, int klane,
                                                 f32x4 acc[4][4]) {
    auto stage_unit = [&](int t, int u) {
        unsigned short* slot = L + (t % 3) * SLOT_E;
        if (u == 0)      stage_half512(A, bm * 256,       aLd, t * 64, slot,         tid);
        else if (u == 1) stage_half512(A, bm * 256 + 128, aLd, t * 64, slot + 8192,  tid);
        else             stage_half512(B, bn * 128,       bLd, t * 64, slot + 16384, tid);
    };

    // prologue: tiles 0 and 1 (6 loads/wave each); wait tile 0 (6 in flight)
    stage_unit(0, 0); stage_unit(0, 1); stage_unit(0, 2);
    stage_unit(1, 0); stage_unit(1, 1); stage_unit(1, 2);
    asm volatile("s_waitcnt vmcnt(6)" ::: "memory");
    __builtin_amdgcn_s_barrier();

    for (int t = 0; t < NT; ++t) {
        const unsigned short* base  = L + (t % 3) * SLOT_E;
        const unsigned short* bbase = base + 16384;
        bf16x8 bv[4][2];
#pragma unroll
        for (int q = 0; q < 4; ++q) {
            if (q == 0) {
#pragma unroll
                for (int n = 0; n < 4; ++n)
#pragma unroll
                    for (int kk = 0; kk < 2; ++kk) {
                        int pr = wn * 64 + n * 16 + frow;
                        bv[n][kk] = *reinterpret_cast<const bf16x8*>(
                            &bbase[pr * 64 + (((kk << 2) + klane) ^ (pr & 7)) * 8]);
                    }
            }
            bf16x8 av[2];
#pragma unroll
            for (int kk = 0; kk < 2; ++kk) {
                int pr = wm * 64 + q * 16 + frow;
                av[kk] = *reinterpret_cast<const bf16x8*>(
                    &base[pr * 64 + (((kk << 2) + klane) ^ (pr & 7)) * 8]);
            }
            if (q < 3 && t + 2 < NT) stage_unit(t + 2, q);
            __builtin_amdgcn_s_barrier();
            __builtin_amdgcn_s_setprio(1);
#pragma unroll
            for (int kk = 0; kk < 2; ++kk)
#pragma unroll
                for (int n = 0; n < 4; ++n)
                    acc[q][n] = __builtin_amdgcn_mfma_f32_16x16x32_bf16(av[kk], bv[n][kk], acc[q][n], 0, 0, 0);
            __builtin_amdgcn_s_setprio(0);
            if (q < 3) __builtin_amdgcn_s_barrier();
        }
        // tile tail: retire tile t+1's loads; keep t+2's 6 in flight
        if (t < NT - 2)       { asm volatile("s_waitcnt vmcnt(6)" ::: "memory"); }
        else if (t == NT - 2) { asm volatile("s_waitcnt vmcnt(0)" ::: "memory"); }
        __builtin_amdgcn_s_barrier();
    }
}

// r-gate: rh = bf16(sigmoid(hb@wr^T + b_r) * hb), strided into A2 col 512+.
__global__ __launch_bounds__(512, 1) void k_rgate_s(const unsigned short* __restrict__ hb,
                                                    const unsigned short* __restrict__ wrb,
                                                    const float* __restrict__ b_r,
                                                    unsigned short* __restrict__ rhA2) {
    __shared__ unsigned short L[3 * SLOT_E];
    int bid = blockIdx.x;
    int swz = (bid & 7) * 64 + (bid >> 3);     // bijective XCD swizzle, nwg=512
    int bm = swz >> 3, bn = swz & 7;
    int tid = threadIdx.x;
    int wave = tid >> 6, lane = tid & 63;
    int wm = wave >> 1, wn = wave & 1;         // 4 x 2 waves
    int frow = lane & 15, klane = lane >> 4;

    f32x4 acc[4][4] = {};
    gemm_pipe<16>(hb, H_DIM, wrb, H_DIM, bm, bn, L, tid, wm, wn, frow, klane, acc);

    int rbase = bm * 256 + wm * 64;
    int cbase = bn * 128 + wn * 64;
#pragma unroll
    for (int q = 0; q < 4; ++q) {
#pragma unroll
        for (int n = 0; n < 4; ++n) {
            int col = cbase + n * 16 + frow;
            float bs = b_r[col];
#pragma unroll
            for (int qq = 0; qq < 4; ++qq) {
                int row = rbase + q * 16 + klane * 4 + qq;
                float g = 1.0f / (1.0f + __expf(-(acc[q][n][qq] + bs)));
                rhA2[(size_t)row * K2 + col] = f2bf(g * bf2f(hb[(size_t)row * H_DIM + col]));
            }
        }
    }
}

// u-gate: u16 = bf16(sigmoid(hb@wu^T + b_u)).
__global__ __launch_bounds__(512, 1) void k_ugate_s(const unsigned short* __restrict__ hb,
                                                    const unsigned short* __restrict__ wub,
                                                    const float* __restrict__ b_u,
                                                    unsigned short* __restrict__ u16) {
    __shared__ unsigned short L[3 * SLOT_E];
    int bid = blockIdx.x;
    int swz = (bid & 7) * 64 + (bid >> 3);
    int bm = swz >> 3, bn = swz & 7;
    int tid = threadIdx.x;
    int wave = tid >> 6, lane = tid & 63;
    int wm = wave >> 1, wn = wave & 1;
    int frow = lane & 15, klane = lane >> 4;

    f32x4 acc[4][4] = {};
    gemm_pipe<16>(hb, H_DIM, wub, H_DIM, bm, bn, L, tid, wm, wn, frow, klane, acc);

    int rbase = bm * 256 + wm * 64;
    int cbase = bn * 128 + wn * 64;
#pragma unroll
    for (int q = 0; q < 4; ++q) {
#pragma unroll
        for (int n = 0; n < 4; ++n) {
            int col = cbase + n * 16 + frow;
            float bs = b_u[col];
#pragma unroll
            for (int qq = 0; qq < 4; ++qq) {
                int row = rbase + q * 16 + klane * 4 + qq;
                float g = 1.0f / (1.0f + __expf(-(acc[q][n][qq] + bs)));
                u16[(size_t)row * H_DIM + col] = f2bf(g);
            }
        }
    }
}

// Candidate + blend: single segment, A2=[x|rh] x W2=[Whx|Whh]^T, K=1536.
__global__ __launch_bounds__(512, 1) void k_cand_b(const unsigned short* __restrict__ a2,
                                                   const unsigned short* __restrict__ w2,
                                                   const unsigned short* __restrict__ hb,
                                                   const unsigned short* __restrict__ u16,
                                                   const float* __restrict__ b_h,
                                                   float* __restrict__ out) {
    __shared__ unsigned short L[3 * SLOT_E];
    int bid = blockIdx.x;
    int swz = (bid & 7) * 64 + (bid >> 3);
    int bm = swz >> 3, bn = swz & 7;
    int tid = threadIdx.x;
    int wave = tid >> 6, lane = tid & 63;
    int wm = wave >> 1, wn = wave & 1;
    int frow = lane & 15, klane = lane >> 4;

    f32x4 acc[4][4] = {};
    gemm_pipe<24>(a2, K2, w2, K2, bm, bn, L, tid, wm, wn, frow, klane, acc);

    int rbase = bm * 256 + wm * 64;
    int cbase = bn * 128 + wn * 64;
#pragma unroll
    for (int q = 0; q < 4; ++q) {
#pragma unroll
        for (int n = 0; n < 4; ++n) {
            int col = cbase + n * 16 + frow;
            float bh = b_h[col];
#pragma unroll
            for (int qq = 0; qq < 4; ++qq) {
                int row = rbase + q * 16 + klane * 4 + qq;
                size_t off = (size_t)row * H_DIM + col;
                float hp = bf2f(hb[off]);
                float u = bf2f(u16[off]);
                float cpre = acc[q][n][qq] + bh;
                cpre = fminf(fmaxf(cpre, -15.0f), 15.0f);
                float e = __expf(2.0f * cpre);
                float c = (e - 1.0f) / (e + 1.0f);
                float h = hp + u * (c - hp);
                out[off] = h;
                out[BH + off] = h;
            }
        }
    }
}

// ===================================================================
// FALLBACK PATH (round-1 kernels, fp32 reg-staged) — used if ws too small
// ===================================================================
#define LDSS 40

static __device__ __forceinline__ void stage_f32(const float* __restrict__ src, int rowBase,
                                                 int ld, int kBase,
                                                 unsigned short* lds, int tid) {
#pragma unroll
    for (int i = 0; i < 4; ++i) {
        int idx = i * 256 + tid;
        int r = idx >> 3, c4 = idx & 7;
        const float4 v = *reinterpret_cast<const float4*>(
            src + (size_t)(rowBase + r) * ld + kBase + c4 * 4);
        uint2 p;
        p.x = (unsigned)f2bf(v.x) | ((unsigned)f2bf(v.y) << 16);
        p.y = (unsigned)f2bf(v.z) | ((unsigned)f2bf(v.w) << 16);
        *reinterpret_cast<uint2*>(lds + r * LDSS + c4 * 4) = p;
    }
}

static __device__ __forceinline__ void stage_bf16s(const unsigned short* __restrict__ src,
                                                   int rowBase, int ld, int kBase,
                                                   unsigned short* lds, int tid) {
#pragma unroll
    for (int i = 0; i < 2; ++i) {
        int idx = i * 256 + tid;
        int r = idx >> 2, c8 = idx & 3;
        const uint4 v = *reinterpret_cast<const uint4*>(
            src + (size_t)(rowBase + r) * ld + kBase + c8 * 8);
        *reinterpret_cast<uint4*>(lds + r * LDSS + c8 * 8) = v;
    }
}

__global__ __launch_bounds__(256, 2) void k_rgate(const float* __restrict__ h_prev,
                                                  const float* __restrict__ W_r,
                                                  const float* __restrict__ b_r,
                                                  unsigned short* __restrict__ rh) {
    __shared__ unsigned short As[128 * LDSS];
    __shared__ unsigned short Bs[128 * LDSS];
    int bid = blockIdx.x;
    int swz = (bid & 7) * 128 + (bid >> 3);
    int bm = swz >> 3, bn = swz & 7;
    int tid = threadIdx.x;
    int wave = tid >> 6, lane = tid & 63;
    int wm = wave >> 1, wn = wave & 1;
    int frow = lane & 15, koff = (lane >> 4) * 8;
    f32x4 acc[4][4] = {};
    for (int ks = 0; ks < H_DIM; ks += 32) {
        stage_f32(h_prev, bm * 128, H_DIM, ks, As, tid);
        stage_f32(W_r, bn * 128, H_DIM, ks, Bs, tid);
        __syncthreads();
        bf16x8 av[4], bv[4];
#pragma unroll
        for (int m = 0; m < 4; ++m)
            av[m] = *reinterpret_cast<const bf16x8*>(&As[(wm * 64 + m * 16 + frow) * LDSS + koff]);
#pragma unroll
        for (int n = 0; n < 4; ++n)
            bv[n] = *reinterpret_cast<const bf16x8*>(&Bs[(wn * 64 + n * 16 + frow) * LDSS + koff]);
#pragma unroll
        for (int m = 0; m < 4; ++m)
#pragma unroll
            for (int n = 0; n < 4; ++n)
                acc[m][n] = __builtin_amdgcn_mfma_f32_16x16x32_bf16(av[m], bv[n], acc[m][n], 0, 0, 0);
        __syncthreads();
    }
    int rbase = bm * 128 + wm * 64, cbase = bn * 128 + wn * 64;
#pragma unroll
    for (int m = 0; m < 4; ++m)
#pragma unroll
        for (int n = 0; n < 4; ++n) {
            int col = cbase + n * 16 + frow;
            float bias = b_r[col];
#pragma unroll
            for (int q = 0; q < 4; ++q) {
                int row = rbase + m * 16 + (lane >> 4) * 4 + q;
                float pre = acc[m][n][q] + bias;
                float rv = 1.0f / (1.0f + __expf(-pre));
                rh[(size_t)row * H_DIM + col] = f2bf(rv * h_prev[(size_t)row * H_DIM + col]);
            }
        }
}

__global__ __launch_bounds__(256, 2) void k_fused(const float* __restrict__ x,
                                                  const float* __restrict__ h_prev,
                                                  const float* __restrict__ W_u,
                                                  const float* __restrict__ b_u,
                                                  const float* __restrict__ W_hx,
                                                  const float* __restrict__ W_hh,
                                                  const float* __restrict__ b_h,
                                                  const unsigned short* __restrict__ rh,
                                                  float* __restrict__ out) {
    __shared__ unsigned short As[128 * LDSS];
    __shared__ unsigned short Bs[128 * LDSS];
    int bid = blockIdx.x;
    int swz = (bid & 7) * 128 + (bid >> 3);
    int bm = swz >> 3, bn = swz & 7;
    int tid = threadIdx.x;
    int wave = tid >> 6, lane = tid & 63;
    int wm = wave >> 1, wn = wave & 1;
    int frow = lane & 15, koff = (lane >> 4) * 8;
    f32x4 accu[4][4] = {};
    f32x4 accc[4][4] = {};
    for (int ks = 0; ks < H_DIM; ks += 32) {
        stage_f32(h_prev, bm * 128, H_DIM, ks, As, tid);
        stage_f32(W_u, bn * 128, H_DIM, ks, Bs, tid);
        __syncthreads();
        bf16x8 av[4], bv[4];
#pragma unroll
        for (int m = 0; m < 4; ++m)
            av[m] = *reinterpret_cast<const bf16x8*>(&As[(wm * 64 + m * 16 + frow) * LDSS + koff]);
#pragma unroll
        for (int n = 0; n < 4; ++n)
            bv[n] = *reinterpret_cast<const bf16x8*>(&Bs[(wn * 64 + n * 16 + frow) * LDSS + koff]);
#pragma unroll
        for (int m = 0; m < 4; ++m)
#pragma unroll
            for (int n = 0; n < 4; ++n)
                accu[m][n] = __builtin_amdgcn_mfma_f32_16x16x32_bf16(av[m], bv[n], accu[m][n], 0, 0, 0);
        __syncthreads();
    }
    for (int ks = 0; ks < IN_DIM; ks += 32) {
        stage_f32(x, bm * 128, IN_DIM, ks, As, tid);
        stage_f32(W_hx, bn * 128, IN_DIM, ks, Bs, tid);
        __syncthreads();
        bf16x8 av[4], bv[4];
#pragma unroll
        for (int m = 0; m < 4; ++m)
            av[m] = *reinterpret_cast<const bf16x8*>(&As[(wm * 64 + m * 16 + frow) * LDSS + koff]);
#pragma unroll
        for (int n = 0; n < 4; ++n)
            bv[n] = *reinterpret_cast<const bf16x8*>(&Bs[(wn * 64 + n * 16 + frow) * LDSS + koff]);
#pragma unroll
        for (int m = 0; m < 4; ++m)
#pragma unroll
            for (int n = 0; n < 4; ++n)
                accc[m][n] = __builtin_amdgcn_mfma_f32_16x16x32_bf16(av[m], bv[n], accc[m][n], 0, 0, 0);
        __syncthreads();
    }
    for (int ks = 0; ks < H_DIM; ks += 32) {
        stage_bf16s(rh, bm * 128, H_DIM, ks, As, tid);
        stage_f32(W_hh, bn * 128, H_DIM, ks, Bs, tid);
        __syncthreads();
        bf16x8 av[4], bv[4];
#pragma unroll
        for (int m = 0; m < 4; ++m)
            av[m] = *reinterpret_cast<const bf16x8*>(&As[(wm * 64 + m * 16 + frow) * LDSS + koff]);
#pragma unroll
        for (int n = 0; n < 4; ++n)
            bv[n] = *reinterpret_cast<const bf16x8*>(&Bs[(wn * 64 + n * 16 + frow) * LDSS + koff]);
#pragma unroll
        for (int m = 0; m < 4; ++m)
#pragma unroll
            for (int n = 0; n < 4; ++n)
                accc[m][n] = __builtin_amdgcn_mfma_f32_16x16x32_bf16(av[m], bv[n], accc[m][n], 0, 0, 0);
        __syncthreads();
    }
    int rbase = bm * 128 + wm * 64, cbase = bn * 128 + wn * 64;
#pragma unroll
    for (int m = 0; m < 4; ++m)
#pragma unroll
        for (int n = 0; n < 4; ++n) {
            int col = cbase + n * 16 + frow;
            float bu = b_u[col], bh = b_h[col];
#pragma unroll
            for (int q = 0; q < 4; ++q) {
                int row = rbase + m * 16 + (lane >> 4) * 4 + q;
                size_t off = (size_t)row * H_DIM + col;
                float hp = h_prev[off];
                float u = 1.0f / (1.0f + __expf(-(accu[m][n][q] + bu)));
                float cpre = accc[m][n][q] + bh;
                cpre = fminf(fmaxf(cpre, -15.0f), 15.0f);
                float e = __expf(2.0f * cpre);
                float c = (e - 1.0f) / (e + 1.0f);
                float h = hp + u * (c - hp);
                out[off] = h;
                out[BH + off] = h;
            }
        }
}

extern "C" void kernel_launch(void* const* d_in, const int* in_sizes, int n_in,
                              void* d_out, int out_size, void* d_ws, size_t ws_size,
                              hipStream_t stream) {
    const float* x      = (const float*)d_in[0];
    const float* h_prev = (const float*)d_in[1];
    const float* W_u    = (const float*)d_in[2];
    const float* b_u    = (const float*)d_in[3];
    const float* W_r    = (const float*)d_in[4];
    const float* b_r    = (const float*)d_in[5];
    const float* W_hx   = (const float*)d_in[6];
    const float* W_hh   = (const float*)d_in[7];
    const float* b_h    = (const float*)d_in[8];
    float* out = (float*)d_out;

    if (ws_size >= WS2_NEED_BYTES) {
        unsigned short* ws = (unsigned short*)d_ws;
        hipLaunchKernelGGL(k_conv, dim3(2048), dim3(256), 0, stream,
                           x, h_prev, W_u, W_hx, W_hh, W_r, ws);
        hipLaunchKernelGGL(k_rgate_s, dim3(512), dim3(512), 0, stream,
                           ws + OFF_HB, ws + OFF_WR, b_r, ws + OFF_A2 + 512);
        hipLaunchKernelGGL(k_ugate_s, dim3(512), dim3(512), 0, stream,
                           ws + OFF_HB, ws + OFF_WU, b_u, ws + OFF_U16);
        hipLaunchKernelGGL(k_cand_b, dim3(512), dim3(512), 0, stream,
                           ws + OFF_A2, ws + OFF_W2, ws + OFF_HB, ws + OFF_U16,
                           b_h, out);
    } else {
        unsigned short* rh = (unsigned short*)d_ws;
        hipLaunchKernelGGL(k_rgate, dim3(1024), dim3(256), 0, stream, h_prev, W_r, b_r, rh);
        hipLaunchKernelGGL(k_fused, dim3(1024), dim3(256), 0, stream,
                           x, h_prev, W_u, b_u, W_hx, W_hh, b_h, rh, out);
    }
}

// Round 9
// 195.551 us; speedup vs baseline: 1.0733x; 1.0733x over previous
//
#include <hip/hip_runtime.h>
#include <hip/hip_bf16.h>

#define M_DIM 16384
#define IN_DIM 512
#define H_DIM 1024
#define BH (M_DIM * H_DIM)
#define K2 1536                            // fused K for cand: 512 (x) + 1024 (rh)

typedef float f32x4 __attribute__((ext_vector_type(4)));
typedef short bf16x8 __attribute__((ext_vector_type(8)));

// ---------------- bf16 helpers ----------------
static __device__ __forceinline__ unsigned short f2bf(float f) {
    union { float f; unsigned u; } a; a.f = f;
    unsigned r = a.u + 0x7fffu + ((a.u >> 16) & 1u);  // RNE
    return (unsigned short)(r >> 16);
}
static __device__ __forceinline__ float bf2f(unsigned short u) {
    union { unsigned u; float f; } a; a.u = (unsigned)u << 16;
    return a.f;
}

// ===================================================================
// ws layout (bf16 elements), total 124.78 MB
// ===================================================================
#define OFF_HB   0u                        // 16384x1024
#define OFF_A2   16777216u                 // 16384x1536: cols 0-511 = x, 512-1535 = rh
#define OFF_WU   41943040u                 // 1024x1024
#define OFF_WR   42991616u                 // 1024x1024
#define OFF_W2   44040192u                 // 1024x1536: cols 0-511 = W_hx, 512-1535 = W_hh
#define OFF_U16  45613056u                 // 16384x1024
#define WS2_ELEMS 62390272u
#define WS2_NEED_BYTES (WS2_ELEMS * 2ull)

// One-pass fp32 -> bf16 conversion of all operands into the fused layout.
__global__ __launch_bounds__(256) void k_conv(const float* __restrict__ x,
                                              const float* __restrict__ h,
                                              const float* __restrict__ wu,
                                              const float* __restrict__ whx,
                                              const float* __restrict__ whh,
                                              const float* __restrict__ wr,
                                              unsigned short* __restrict__ ws) {
    const int total = 3604480;  // total 8-elem units
    for (int u = blockIdx.x * blockDim.x + threadIdx.x; u < total;
         u += gridDim.x * blockDim.x) {
        const float* src; unsigned short* d; int lu;
        if (u < 2097152)      { lu = u;
                                src = h + (size_t)lu * 8;
                                d = ws + OFF_HB + (size_t)lu * 8; }
        else if (u < 3145728) { lu = u - 2097152;                       // x -> A2 strided
                                src = x + (size_t)lu * 8;
                                d = ws + OFF_A2 + (size_t)(lu >> 6) * K2 + (lu & 63) * 8; }
        else if (u < 3276800) { lu = u - 3145728;
                                src = wu + (size_t)lu * 8;
                                d = ws + OFF_WU + (size_t)lu * 8; }
        else if (u < 3342336) { lu = u - 3276800;                       // whx -> W2 strided
                                src = whx + (size_t)lu * 8;
                                d = ws + OFF_W2 + (size_t)(lu >> 6) * K2 + (lu & 63) * 8; }
        else if (u < 3473408) { lu = u - 3342336;                       // whh -> W2 + 512
                                src = whh + (size_t)lu * 8;
                                d = ws + OFF_W2 + (size_t)(lu >> 7) * K2 + 512 + (lu & 127) * 8; }
        else                  { lu = u - 3473408;
                                src = wr + (size_t)lu * 8;
                                d = ws + OFF_WR + (size_t)lu * 8; }
        float4 a = *reinterpret_cast<const float4*>(src);
        float4 b = *reinterpret_cast<const float4*>(src + 4);
        uint4 p;
        p.x = (unsigned)f2bf(a.x) | ((unsigned)f2bf(a.y) << 16);
        p.y = (unsigned)f2bf(a.z) | ((unsigned)f2bf(a.w) << 16);
        p.z = (unsigned)f2bf(b.x) | ((unsigned)f2bf(b.y) << 16);
        p.w = (unsigned)f2bf(b.z) | ((unsigned)f2bf(b.w) << 16);
        *reinterpret_cast<uint4*>(d) = p;
    }
}

// Stage a 128x64 bf16 tile into linear LDS via global_load_lds width-16, with the
// chunk-column involution kc ^ (row&7) applied on the GLOBAL side (rule #21).
static __device__ __forceinline__ void stage_lds(const unsigned short* __restrict__ src,
                                                 int rowBase, int ld, int ks,
                                                 unsigned short* lds, int tid) {
#pragma unroll
    for (int i = 0; i < 4; ++i) {
        int c = i * 256 + tid;           // 16B-chunk id in [0,1024): 128 rows x 8 chunks
        int r = c >> 3, kc = c & 7;
        int gc = kc ^ (r & 7);           // involution
        const unsigned short* g = src + (size_t)(rowBase + r) * ld + ks + gc * 8;
        unsigned short* l = lds + c * 8;
        __builtin_amdgcn_global_load_lds((const __attribute__((address_space(1))) void*)g,
                                         (__attribute__((address_space(3))) void*)l,
                                         16, 0, 0);
    }
}

// One GEMM segment (proven r2/r3/r7 structure): C[128x128] += A x B^T, BK=64.
template <int KSEG>
static __device__ __forceinline__ void gemm_seg(const unsigned short* __restrict__ A, int aLd,
                                                const unsigned short* __restrict__ B, int bLd,
                                                int bm, int bn,
                                                unsigned short* As, unsigned short* Bs,
                                                int tid, int wm, int wn, int frow, int klane,
                                                f32x4 acc[4][4]) {
    for (int ks = 0; ks < KSEG; ks += 64) {
        stage_lds(A, bm * 128, aLd, ks, As, tid);
        stage_lds(B, bn * 128, bLd, ks, Bs, tid);
        __syncthreads();
#pragma unroll
        for (int kk = 0; kk < 2; ++kk) {
            bf16x8 av[4], bv[4];
#pragma unroll
            for (int m = 0; m < 4; ++m) {
                int pr = wm * 64 + m * 16 + frow;
                av[m] = *reinterpret_cast<const bf16x8*>(
                    &As[pr * 64 + (((kk << 2) + klane) ^ (pr & 7)) * 8]);
            }
#pragma unroll
            for (int n = 0; n < 4; ++n) {
                int pr = wn * 64 + n * 16 + frow;
                bv[n] = *reinterpret_cast<const bf16x8*>(
                    &Bs[pr * 64 + (((kk << 2) + klane) ^ (pr & 7)) * 8]);
            }
#pragma unroll
            for (int m = 0; m < 4; ++m)
#pragma unroll
                for (int n = 0; n < 4; ++n)
                    acc[m][n] = __builtin_amdgcn_mfma_f32_16x16x32_bf16(av[m], bv[n], acc[m][n], 0, 0, 0);
        }
        __syncthreads();
    }
}

// Merged gates GEMM: blocks [0,1024) compute r-gate, [1024,2048) compute u-gate.
// Block-range split (NOT bn-interleave like r6): r blocks dispatch first, so the
// two weight panels are mostly NOT concurrently live per XCD L2.
__global__ __launch_bounds__(256, 3) void k_gates2(const unsigned short* __restrict__ hb,
                                                   const unsigned short* __restrict__ wrb,
                                                   const unsigned short* __restrict__ wub,
                                                   const float* __restrict__ b_r,
                                                   const float* __restrict__ b_u,
                                                   unsigned short* __restrict__ rhA2,
                                                   unsigned short* __restrict__ u16) {
    __shared__ unsigned short As[128 * 64];
    __shared__ unsigned short Bs[128 * 64];

    int bid = blockIdx.x;
    bool isR = bid < 1024;
    int lb = isR ? bid : bid - 1024;
    int swz = (lb & 7) * 128 + (lb >> 3);     // bijective XCD swizzle within each half
    int bm = swz >> 3, bn = swz & 7;
    const unsigned short* wsrc = isR ? wrb : wub;
    const float* bias = isR ? b_r : b_u;

    int tid = threadIdx.x;
    int wave = tid >> 6, lane = tid & 63;
    int wm = wave >> 1, wn = wave & 1;
    int frow = lane & 15, klane = lane >> 4;

    f32x4 acc[4][4] = {};
    gemm_seg<H_DIM>(hb, H_DIM, wsrc, H_DIM, bm, bn, As, Bs, tid, wm, wn, frow, klane, acc);

    int rbase = bm * 128 + wm * 64;
    int cbase = bn * 128 + wn * 64;
#pragma unroll
    for (int m = 0; m < 4; ++m) {
#pragma unroll
        for (int n = 0; n < 4; ++n) {
            int col = cbase + n * 16 + frow;
            float bs = bias[col];
#pragma unroll
            for (int q = 0; q < 4; ++q) {
                int row = rbase + m * 16 + klane * 4 + q;
                float g = 1.0f / (1.0f + __expf(-(acc[m][n][q] + bs)));
                if (isR)
                    rhA2[(size_t)row * K2 + col] = f2bf(g * bf2f(hb[(size_t)row * H_DIM + col]));
                else
                    u16[(size_t)row * H_DIM + col] = f2bf(g);
            }
        }
    }
}

// Candidate GEMM + blend: single segment, A2=[x|rh] (ld 1536) x W2=[Whx|Whh]^T.
// launch_bounds(256,4): +1 resident block/CU vs r7 to hide stage/epilogue latency.
__global__ __launch_bounds__(256, 4) void k_cand_b(const unsigned short* __restrict__ a2,
                                                   const unsigned short* __restrict__ w2,
                                                   const unsigned short* __restrict__ hb,
                                                   const unsigned short* __restrict__ u16,
                                                   const float* __restrict__ b_h,
                                                   float* __restrict__ out) {
    __shared__ unsigned short As[128 * 64];
    __shared__ unsigned short Bs[128 * 64];

    int bid = blockIdx.x;
    int swz = (bid & 7) * 128 + (bid >> 3);   // bijective XCD swizzle, nwg=1024
    int bm = swz >> 3, bn = swz & 7;

    int tid = threadIdx.x;
    int wave = tid >> 6, lane = tid & 63;
    int wm = wave >> 1, wn = wave & 1;
    int frow = lane & 15, klane = lane >> 4;

    f32x4 acc[4][4] = {};
    gemm_seg<K2>(a2, K2, w2, K2, bm, bn, As, Bs, tid, wm, wn, frow, klane, acc);

    int rbase = bm * 128 + wm * 64;
    int cbase = bn * 128 + wn * 64;
#pragma unroll
    for (int m = 0; m < 4; ++m) {
#pragma unroll
        for (int n = 0; n < 4; ++n) {
            int col = cbase + n * 16 + frow;
            float bh = b_h[col];
#pragma unroll
            for (int q = 0; q < 4; ++q) {
                int row = rbase + m * 16 + klane * 4 + q;
                size_t off = (size_t)row * H_DIM + col;
                float hp = bf2f(hb[off]);
                float u = bf2f(u16[off]);
                float cpre = acc[m][n][q] + bh;
                cpre = fminf(fmaxf(cpre, -15.0f), 15.0f);
                float e = __expf(2.0f * cpre);
                float c = (e - 1.0f) / (e + 1.0f);
                float h = hp + u * (c - hp);
                out[off] = h;
                out[BH + off] = h;
            }
        }
    }
}

// ===================================================================
// FALLBACK PATH (round-1 kernels, fp32 reg-staged) — used if ws too small
// ===================================================================
#define LDSS 40

static __device__ __forceinline__ void stage_f32(const float* __restrict__ src, int rowBase,
                                                 int ld, int kBase,
                                                 unsigned short* lds, int tid) {
#pragma unroll
    for (int i = 0; i < 4; ++i) {
        int idx = i * 256 + tid;
        int r = idx >> 3, c4 = idx & 7;
        const float4 v = *reinterpret_cast<const float4*>(
            src + (size_t)(rowBase + r) * ld + kBase + c4 * 4);
        uint2 p;
        p.x = (unsigned)f2bf(v.x) | ((unsigned)f2bf(v.y) << 16);
        p.y = (unsigned)f2bf(v.z) | ((unsigned)f2bf(v.w) << 16);
        *reinterpret_cast<uint2*>(lds + r * LDSS + c4 * 4) = p;
    }
}

static __device__ __forceinline__ void stage_bf16s(const unsigned short* __restrict__ src,
                                                   int rowBase, int ld, int kBase,
                                                   unsigned short* lds, int tid) {
#pragma unroll
    for (int i = 0; i < 2; ++i) {
        int idx = i * 256 + tid;
        int r = idx >> 2, c8 = idx & 3;
        const uint4 v = *reinterpret_cast<const uint4*>(
            src + (size_t)(rowBase + r) * ld + kBase + c8 * 8);
        *reinterpret_cast<uint4*>(lds + r * LDSS + c8 * 8) = v;
    }
}

__global__ __launch_bounds__(256, 2) void k_rgate(const float* __restrict__ h_prev,
                                                  const float* __restrict__ W_r,
                                                  const float* __restrict__ b_r,
                                                  unsigned short* __restrict__ rh) {
    __shared__ unsigned short As[128 * LDSS];
    __shared__ unsigned short Bs[128 * LDSS];
    int bid = blockIdx.x;
    int swz = (bid & 7) * 128 + (bid >> 3);
    int bm = swz >> 3, bn = swz & 7;
    int tid = threadIdx.x;
    int wave = tid >> 6, lane = tid & 63;
    int wm = wave >> 1, wn = wave & 1;
    int frow = lane & 15, koff = (lane >> 4) * 8;
    f32x4 acc[4][4] = {};
    for (int ks = 0; ks < H_DIM; ks += 32) {
        stage_f32(h_prev, bm * 128, H_DIM, ks, As, tid);
        stage_f32(W_r, bn * 128, H_DIM, ks, Bs, tid);
        __syncthreads();
        bf16x8 av[4], bv[4];
#pragma unroll
        for (int m = 0; m < 4; ++m)
            av[m] = *reinterpret_cast<const bf16x8*>(&As[(wm * 64 + m * 16 + frow) * LDSS + koff]);
#pragma unroll
        for (int n = 0; n < 4; ++n)
            bv[n] = *reinterpret_cast<const bf16x8*>(&Bs[(wn * 64 + n * 16 + frow) * LDSS + koff]);
#pragma unroll
        for (int m = 0; m < 4; ++m)
#pragma unroll
            for (int n = 0; n < 4; ++n)
                acc[m][n] = __builtin_amdgcn_mfma_f32_16x16x32_bf16(av[m], bv[n], acc[m][n], 0, 0, 0);
        __syncthreads();
    }
    int rbase = bm * 128 + wm * 64, cbase = bn * 128 + wn * 64;
#pragma unroll
    for (int m = 0; m < 4; ++m)
#pragma unroll
        for (int n = 0; n < 4; ++n) {
            int col = cbase + n * 16 + frow;
            float bias = b_r[col];
#pragma unroll
            for (int q = 0; q < 4; ++q) {
                int row = rbase + m * 16 + (lane >> 4) * 4 + q;
                float pre = acc[m][n][q] + bias;
                float rv = 1.0f / (1.0f + __expf(-pre));
                rh[(size_t)row * H_DIM + col] = f2bf(rv * h_prev[(size_t)row * H_DIM + col]);
            }
        }
}

__global__ __launch_bounds__(256, 2) void k_fused(const float* __restrict__ x,
                                                  const float* __restrict__ h_prev,
                                                  const float* __restrict__ W_u,
                                                  const float* __restrict__ b_u,
                                                  const float* __restrict__ W_hx,
                                                  const float* __restrict__ W_hh,
                                                  const float* __restrict__ b_h,
                                                  const unsigned short* __restrict__ rh,
                                                  float* __restrict__ out) {
    __shared__ unsigned short As[128 * LDSS];
    __shared__ unsigned short Bs[128 * LDSS];
    int bid = blockIdx.x;
    int swz = (bid & 7) * 128 + (bid >> 3);
    int bm = swz >> 3, bn = swz & 7;
    int tid = threadIdx.x;
    int wave = tid >> 6, lane = tid & 63;
    int wm = wave >> 1, wn = wave & 1;
    int frow = lane & 15, koff = (lane >> 4) * 8;
    f32x4 accu[4][4] = {};
    f32x4 accc[4][4] = {};
    for (int ks = 0; ks < H_DIM; ks += 32) {
        stage_f32(h_prev, bm * 128, H_DIM, ks, As, tid);
        stage_f32(W_u, bn * 128, H_DIM, ks, Bs, tid);
        __syncthreads();
        bf16x8 av[4], bv[4];
#pragma unroll
        for (int m = 0; m < 4; ++m)
            av[m] = *reinterpret_cast<const bf16x8*>(&As[(wm * 64 + m * 16 + frow) * LDSS + koff]);
#pragma unroll
        for (int n = 0; n < 4; ++n)
            bv[n] = *reinterpret_cast<const bf16x8*>(&Bs[(wn * 64 + n * 16 + frow) * LDSS + koff]);
#pragma unroll
        for (int m = 0; m < 4; ++m)
#pragma unroll
            for (int n = 0; n < 4; ++n)
                accu[m][n] = __builtin_amdgcn_mfma_f32_16x16x32_bf16(av[m], bv[n], accu[m][n], 0, 0, 0);
        __syncthreads();
    }
    for (int ks = 0; ks < IN_DIM; ks += 32) {
        stage_f32(x, bm * 128, IN_DIM, ks, As, tid);
        stage_f32(W_hx, bn * 128, IN_DIM, ks, Bs, tid);
        __syncthreads();
        bf16x8 av[4], bv[4];
#pragma unroll
        for (int m = 0; m < 4; ++m)
            av[m] = *reinterpret_cast<const bf16x8*>(&As[(wm * 64 + m * 16 + frow) * LDSS + koff]);
#pragma unroll
        for (int n = 0; n < 4; ++n)
            bv[n] = *reinterpret_cast<const bf16x8*>(&Bs[(wn * 64 + n * 16 + frow) * LDSS + koff]);
#pragma unroll
        for (int m = 0; m < 4; ++m)
#pragma unroll
            for (int n = 0; n < 4; ++n)
                accc[m][n] = __builtin_amdgcn_mfma_f32_16x16x32_bf16(av[m], bv[n], accc[m][n], 0, 0, 0);
        __syncthreads();
    }
    for (int ks = 0; ks < H_DIM; ks += 32) {
        stage_bf16s(rh, bm * 128, H_DIM, ks, As, tid);
        stage_f32(W_hh, bn * 128, H_DIM, ks, Bs, tid);
        __syncthreads();
        bf16x8 av[4], bv[4];
#pragma unroll
        for (int m = 0; m < 4; ++m)
            av[m] = *reinterpret_cast<const bf16x8*>(&As[(wm * 64 + m * 16 + frow) * LDSS + koff]);
#pragma unroll
        for (int n = 0; n < 4; ++n)
            bv[n] = *reinterpret_cast<const bf16x8*>(&Bs[(wn * 64 + n * 16 + frow) * LDSS + koff]);
#pragma unroll
        for (int m = 0; m < 4; ++m)
#pragma unroll
            for (int n = 0; n < 4; ++n)
                accc[m][n] = __builtin_amdgcn_mfma_f32_16x16x32_bf16(av[m], bv[n], accc[m][n], 0, 0, 0);
        __syncthreads();
    }
    int rbase = bm * 128 + wm * 64, cbase = bn * 128 + wn * 64;
#pragma unroll
    for (int m = 0; m < 4; ++m)
#pragma unroll
        for (int n = 0; n < 4; ++n) {
            int col = cbase + n * 16 + frow;
            float bu = b_u[col], bh = b_h[col];
#pragma unroll
            for (int q = 0; q < 4; ++q) {
                int row = rbase + m * 16 + (lane >> 4) * 4 + q;
                size_t off = (size_t)row * H_DIM + col;
                float hp = h_prev[off];
                float u = 1.0f / (1.0f + __expf(-(accu[m][n][q] + bu)));
                float cpre = accc[m][n][q] + bh;
                cpre = fminf(fmaxf(cpre, -15.0f), 15.0f);
                float e = __expf(2.0f * cpre);
                float c = (e - 1.0f) / (e + 1.0f);
                float h = hp + u * (c - hp);
                out[off] = h;
                out[BH + off] = h;
            }
        }
}

extern "C" void kernel_launch(void* const* d_in, const int* in_sizes, int n_in,
                              void* d_out, int out_size, void* d_ws, size_t ws_size,
                              hipStream_t stream) {
    const float* x      = (const float*)d_in[0];
    const float* h_prev = (const float*)d_in[1];
    const float* W_u    = (const float*)d_in[2];
    const float* b_u    = (const float*)d_in[3];
    const float* W_r    = (const float*)d_in[4];
    const float* b_r    = (const float*)d_in[5];
    const float* W_hx   = (const float*)d_in[6];
    const float* W_hh   = (const float*)d_in[7];
    const float* b_h    = (const float*)d_in[8];
    float* out = (float*)d_out;

    if (ws_size >= WS2_NEED_BYTES) {
        unsigned short* ws = (unsigned short*)d_ws;
        hipLaunchKernelGGL(k_conv, dim3(2048), dim3(256), 0, stream,
                           x, h_prev, W_u, W_hx, W_hh, W_r, ws);
        hipLaunchKernelGGL(k_gates2, dim3(2048), dim3(256), 0, stream,
                           ws + OFF_HB, ws + OFF_WR, ws + OFF_WU, b_r, b_u,
                           ws + OFF_A2 + 512, ws + OFF_U16);
        hipLaunchKernelGGL(k_cand_b, dim3(1024), dim3(256), 0, stream,
                           ws + OFF_A2, ws + OFF_W2, ws + OFF_HB, ws + OFF_U16,
                           b_h, out);
    } else {
        unsigned short* rh = (unsigned short*)d_ws;
        hipLaunchKernelGGL(k_rgate, dim3(1024), dim3(256), 0, stream, h_prev, W_r, b_r, rh);
        hipLaunchKernelGGL(k_fused, dim3(1024), dim3(256), 0, stream,
                           x, h_prev, W_u, b_u, W_hx, W_hh, b_h, rh, out);
    }
}

// Round 10
// 186.543 us; speedup vs baseline: 1.1252x; 1.0483x over previous
//
#include <hip/hip_runtime.h>
#include <hip/hip_bf16.h>

#define M_DIM 16384
#define IN_DIM 512
#define H_DIM 1024
#define BH (M_DIM * H_DIM)
#define K2 1536                            // fused K for cand: 512 (x) + 1024 (rh)

typedef float f32x4 __attribute__((ext_vector_type(4)));
typedef short bf16x8 __attribute__((ext_vector_type(8)));

// ---------------- bf16 helpers ----------------
static __device__ __forceinline__ unsigned short f2bf(float f) {
    union { float f; unsigned u; } a; a.f = f;
    unsigned r = a.u + 0x7fffu + ((a.u >> 16) & 1u);  // RNE
    return (unsigned short)(r >> 16);
}
static __device__ __forceinline__ float bf2f(unsigned short u) {
    union { unsigned u; float f; } a; a.u = (unsigned)u << 16;
    return a.f;
}

// ===================================================================
// ws layout (bf16 elements), total 124.78 MB
// ===================================================================
#define OFF_HB   0u                        // 16384x1024
#define OFF_A2   16777216u                 // 16384x1536: cols 0-511 = x, 512-1535 = rh
#define OFF_WU   41943040u                 // 1024x1024
#define OFF_WR   42991616u                 // 1024x1024
#define OFF_W2   44040192u                 // 1024x1536: cols 0-511 = W_hx, 512-1535 = W_hh
#define OFF_U16  45613056u                 // 16384x1024
#define WS2_ELEMS 62390272u
#define WS2_NEED_BYTES (WS2_ELEMS * 2ull)

// One-pass fp32 -> bf16 conversion of all operands into the fused layout.
__global__ __launch_bounds__(256) void k_conv(const float* __restrict__ x,
                                              const float* __restrict__ h,
                                              const float* __restrict__ wu,
                                              const float* __restrict__ whx,
                                              const float* __restrict__ whh,
                                              const float* __restrict__ wr,
                                              unsigned short* __restrict__ ws) {
    const int total = 3604480;  // total 8-elem units
    for (int u = blockIdx.x * blockDim.x + threadIdx.x; u < total;
         u += gridDim.x * blockDim.x) {
        const float* src; unsigned short* d; int lu;
        if (u < 2097152)      { lu = u;
                                src = h + (size_t)lu * 8;
                                d = ws + OFF_HB + (size_t)lu * 8; }
        else if (u < 3145728) { lu = u - 2097152;                       // x -> A2 strided
                                src = x + (size_t)lu * 8;
                                d = ws + OFF_A2 + (size_t)(lu >> 6) * K2 + (lu & 63) * 8; }
        else if (u < 3276800) { lu = u - 3145728;
                                src = wu + (size_t)lu * 8;
                                d = ws + OFF_WU + (size_t)lu * 8; }
        else if (u < 3342336) { lu = u - 3276800;                       // whx -> W2 strided
                                src = whx + (size_t)lu * 8;
                                d = ws + OFF_W2 + (size_t)(lu >> 6) * K2 + (lu & 63) * 8; }
        else if (u < 3473408) { lu = u - 3342336;                       // whh -> W2 + 512
                                src = whh + (size_t)lu * 8;
                                d = ws + OFF_W2 + (size_t)(lu >> 7) * K2 + 512 + (lu & 127) * 8; }
        else                  { lu = u - 3473408;
                                src = wr + (size_t)lu * 8;
                                d = ws + OFF_WR + (size_t)lu * 8; }
        float4 a = *reinterpret_cast<const float4*>(src);
        float4 b = *reinterpret_cast<const float4*>(src + 4);
        uint4 p;
        p.x = (unsigned)f2bf(a.x) | ((unsigned)f2bf(a.y) << 16);
        p.y = (unsigned)f2bf(a.z) | ((unsigned)f2bf(a.w) << 16);
        p.z = (unsigned)f2bf(b.x) | ((unsigned)f2bf(b.y) << 16);
        p.w = (unsigned)f2bf(b.z) | ((unsigned)f2bf(b.w) << 16);
        *reinterpret_cast<uint4*>(d) = p;
    }
}

// Stage a 128x64 bf16 tile into linear LDS via global_load_lds width-16, with the
// chunk-column involution kc ^ (row&7) applied on the GLOBAL side (rule #21).
static __device__ __forceinline__ void stage_lds(const unsigned short* __restrict__ src,
                                                 int rowBase, int ld, int ks,
                                                 unsigned short* lds, int tid) {
#pragma unroll
    for (int i = 0; i < 4; ++i) {
        int c = i * 256 + tid;           // 16B-chunk id in [0,1024): 128 rows x 8 chunks
        int r = c >> 3, kc = c & 7;
        int gc = kc ^ (r & 7);           // involution
        const unsigned short* g = src + (size_t)(rowBase + r) * ld + ks + gc * 8;
        unsigned short* l = lds + c * 8;
        __builtin_amdgcn_global_load_lds((const __attribute__((address_space(1))) void*)g,
                                         (__attribute__((address_space(3))) void*)l,
                                         16, 0, 0);
    }
}

// One GEMM segment (proven r2/r3/r7 structure): C[128x128] += A x B^T, BK=64.
template <int KSEG>
static __device__ __forceinline__ void gemm_seg(const unsigned short* __restrict__ A, int aLd,
                                                const unsigned short* __restrict__ B, int bLd,
                                                int bm, int bn,
                                                unsigned short* As, unsigned short* Bs,
                                                int tid, int wm, int wn, int frow, int klane,
                                                f32x4 acc[4][4]) {
    for (int ks = 0; ks < KSEG; ks += 64) {
        stage_lds(A, bm * 128, aLd, ks, As, tid);
        stage_lds(B, bn * 128, bLd, ks, Bs, tid);
        __syncthreads();
#pragma unroll
        for (int kk = 0; kk < 2; ++kk) {
            bf16x8 av[4], bv[4];
#pragma unroll
            for (int m = 0; m < 4; ++m) {
                int pr = wm * 64 + m * 16 + frow;
                av[m] = *reinterpret_cast<const bf16x8*>(
                    &As[pr * 64 + (((kk << 2) + klane) ^ (pr & 7)) * 8]);
            }
#pragma unroll
            for (int n = 0; n < 4; ++n) {
                int pr = wn * 64 + n * 16 + frow;
                bv[n] = *reinterpret_cast<const bf16x8*>(
                    &Bs[pr * 64 + (((kk << 2) + klane) ^ (pr & 7)) * 8]);
            }
#pragma unroll
            for (int m = 0; m < 4; ++m)
#pragma unroll
                for (int n = 0; n < 4; ++n)
                    acc[m][n] = __builtin_amdgcn_mfma_f32_16x16x32_bf16(av[m], bv[n], acc[m][n], 0, 0, 0);
        }
        __syncthreads();
    }
}

// r-gate GEMM (nwg=1024, occ-4): rh = bf16(sigmoid(hb@wr^T + b_r) * hb),
// written STRIDED into A2 col 512+ (so cand stays single-segment K=1536).
__global__ __launch_bounds__(256, 4) void k_rgate_s(const unsigned short* __restrict__ hb,
                                                    const unsigned short* __restrict__ wrb,
                                                    const float* __restrict__ b_r,
                                                    unsigned short* __restrict__ rhA2) {
    __shared__ unsigned short As[128 * 64];
    __shared__ unsigned short Bs[128 * 64];

    int bid = blockIdx.x;
    int swz = (bid & 7) * 128 + (bid >> 3);   // bijective XCD swizzle, nwg=1024
    int bm = swz >> 3, bn = swz & 7;

    int tid = threadIdx.x;
    int wave = tid >> 6, lane = tid & 63;
    int wm = wave >> 1, wn = wave & 1;
    int frow = lane & 15, klane = lane >> 4;

    f32x4 acc[4][4] = {};
    gemm_seg<H_DIM>(hb, H_DIM, wrb, H_DIM, bm, bn, As, Bs, tid, wm, wn, frow, klane, acc);

    int rbase = bm * 128 + wm * 64;
    int cbase = bn * 128 + wn * 64;
#pragma unroll
    for (int m = 0; m < 4; ++m) {
#pragma unroll
        for (int n = 0; n < 4; ++n) {
            int col = cbase + n * 16 + frow;
            float bs = b_r[col];
#pragma unroll
            for (int q = 0; q < 4; ++q) {
                int row = rbase + m * 16 + klane * 4 + q;
                float g = 1.0f / (1.0f + __expf(-(acc[m][n][q] + bs)));
                rhA2[(size_t)row * K2 + col] = f2bf(g * bf2f(hb[(size_t)row * H_DIM + col]));
            }
        }
    }
}

// u-gate GEMM (nwg=1024, occ-4): u16 = bf16(sigmoid(hb@wu^T + b_u)), linear.
__global__ __launch_bounds__(256, 4) void k_ugate_s(const unsigned short* __restrict__ hb,
                                                    const unsigned short* __restrict__ wub,
                                                    const float* __restrict__ b_u,
                                                    unsigned short* __restrict__ u16) {
    __shared__ unsigned short As[128 * 64];
    __shared__ unsigned short Bs[128 * 64];

    int bid = blockIdx.x;
    int swz = (bid & 7) * 128 + (bid >> 3);   // bijective XCD swizzle, nwg=1024
    int bm = swz >> 3, bn = swz & 7;

    int tid = threadIdx.x;
    int wave = tid >> 6, lane = tid & 63;
    int wm = wave >> 1, wn = wave & 1;
    int frow = lane & 15, klane = lane >> 4;

    f32x4 acc[4][4] = {};
    gemm_seg<H_DIM>(hb, H_DIM, wub, H_DIM, bm, bn, As, Bs, tid, wm, wn, frow, klane, acc);

    int rbase = bm * 128 + wm * 64;
    int cbase = bn * 128 + wn * 64;
#pragma unroll
    for (int m = 0; m < 4; ++m) {
#pragma unroll
        for (int n = 0; n < 4; ++n) {
            int col = cbase + n * 16 + frow;
            float bs = b_u[col];
#pragma unroll
            for (int q = 0; q < 4; ++q) {
                int row = rbase + m * 16 + klane * 4 + q;
                float g = 1.0f / (1.0f + __expf(-(acc[m][n][q] + bs)));
                u16[(size_t)row * H_DIM + col] = f2bf(g);
            }
        }
    }
}

// Candidate GEMM + blend (occ-4): single segment, A2=[x|rh] x W2=[Whx|Whh]^T.
__global__ __launch_bounds__(256, 4) void k_cand_b(const unsigned short* __restrict__ a2,
                                                   const unsigned short* __restrict__ w2,
                                                   const unsigned short* __restrict__ hb,
                                                   const unsigned short* __restrict__ u16,
                                                   const float* __restrict__ b_h,
                                                   float* __restrict__ out) {
    __shared__ unsigned short As[128 * 64];
    __shared__ unsigned short Bs[128 * 64];

    int bid = blockIdx.x;
    int swz = (bid & 7) * 128 + (bid >> 3);   // bijective XCD swizzle, nwg=1024
    int bm = swz >> 3, bn = swz & 7;

    int tid = threadIdx.x;
    int wave = tid >> 6, lane = tid & 63;
    int wm = wave >> 1, wn = wave & 1;
    int frow = lane & 15, klane = lane >> 4;

    f32x4 acc[4][4] = {};
    gemm_seg<K2>(a2, K2, w2, K2, bm, bn, As, Bs, tid, wm, wn, frow, klane, acc);

    int rbase = bm * 128 + wm * 64;
    int cbase = bn * 128 + wn * 64;
#pragma unroll
    for (int m = 0; m < 4; ++m) {
#pragma unroll
        for (int n = 0; n < 4; ++n) {
            int col = cbase + n * 16 + frow;
            float bh = b_h[col];
#pragma unroll
            for (int q = 0; q < 4; ++q) {
                int row = rbase + m * 16 + klane * 4 + q;
                size_t off = (size_t)row * H_DIM + col;
                float hp = bf2f(hb[off]);
                float u = bf2f(u16[off]);
                float cpre = acc[m][n][q] + bh;
                cpre = fminf(fmaxf(cpre, -15.0f), 15.0f);
                float e = __expf(2.0f * cpre);
                float c = (e - 1.0f) / (e + 1.0f);
                float h = hp + u * (c - hp);
                out[off] = h;
                out[BH + off] = h;
            }
        }
    }
}

// ===================================================================
// FALLBACK PATH (round-1 kernels, fp32 reg-staged) — used if ws too small
// ===================================================================
#define LDSS 40

static __device__ __forceinline__ void stage_f32(const float* __restrict__ src, int rowBase,
                                                 int ld, int kBase,
                                                 unsigned short* lds, int tid) {
#pragma unroll
    for (int i = 0; i < 4; ++i) {
        int idx = i * 256 + tid;
        int r = idx >> 3, c4 = idx & 7;
        const float4 v = *reinterpret_cast<const float4*>(
            src + (size_t)(rowBase + r) * ld + kBase + c4 * 4);
        uint2 p;
        p.x = (unsigned)f2bf(v.x) | ((unsigned)f2bf(v.y) << 16);
        p.y = (unsigned)f2bf(v.z) | ((unsigned)f2bf(v.w) << 16);
        *reinterpret_cast<uint2*>(lds + r * LDSS + c4 * 4) = p;
    }
}

static __device__ __forceinline__ void stage_bf16s(const unsigned short* __restrict__ src,
                                                   int rowBase, int ld, int kBase,
                                                   unsigned short* lds, int tid) {
#pragma unroll
    for (int i = 0; i < 2; ++i) {
        int idx = i * 256 + tid;
        int r = idx >> 2, c8 = idx & 3;
        const uint4 v = *reinterpret_cast<const uint4*>(
            src + (size_t)(rowBase + r) * ld + kBase + c8 * 8);
        *reinterpret_cast<uint4*>(lds + r * LDSS + c8 * 8) = v;
    }
}

__global__ __launch_bounds__(256, 2) void k_rgate(const float* __restrict__ h_prev,
                                                  const float* __restrict__ W_r,
                                                  const float* __restrict__ b_r,
                                                  unsigned short* __restrict__ rh) {
    __shared__ unsigned short As[128 * LDSS];
    __shared__ unsigned short Bs[128 * LDSS];
    int bid = blockIdx.x;
    int swz = (bid & 7) * 128 + (bid >> 3);
    int bm = swz >> 3, bn = swz & 7;
    int tid = threadIdx.x;
    int wave = tid >> 6, lane = tid & 63;
    int wm = wave >> 1, wn = wave & 1;
    int frow = lane & 15, koff = (lane >> 4) * 8;
    f32x4 acc[4][4] = {};
    for (int ks = 0; ks < H_DIM; ks += 32) {
        stage_f32(h_prev, bm * 128, H_DIM, ks, As, tid);
        stage_f32(W_r, bn * 128, H_DIM, ks, Bs, tid);
        __syncthreads();
        bf16x8 av[4], bv[4];
#pragma unroll
        for (int m = 0; m < 4; ++m)
            av[m] = *reinterpret_cast<const bf16x8*>(&As[(wm * 64 + m * 16 + frow) * LDSS + koff]);
#pragma unroll
        for (int n = 0; n < 4; ++n)
            bv[n] = *reinterpret_cast<const bf16x8*>(&Bs[(wn * 64 + n * 16 + frow) * LDSS + koff]);
#pragma unroll
        for (int m = 0; m < 4; ++m)
#pragma unroll
            for (int n = 0; n < 4; ++n)
                acc[m][n] = __builtin_amdgcn_mfma_f32_16x16x32_bf16(av[m], bv[n], acc[m][n], 0, 0, 0);
        __syncthreads();
    }
    int rbase = bm * 128 + wm * 64, cbase = bn * 128 + wn * 64;
#pragma unroll
    for (int m = 0; m < 4; ++m)
#pragma unroll
        for (int n = 0; n < 4; ++n) {
            int col = cbase + n * 16 + frow;
            float bias = b_r[col];
#pragma unroll
            for (int q = 0; q < 4; ++q) {
                int row = rbase + m * 16 + (lane >> 4) * 4 + q;
                float pre = acc[m][n][q] + bias;
                float rv = 1.0f / (1.0f + __expf(-pre));
                rh[(size_t)row * H_DIM + col] = f2bf(rv * h_prev[(size_t)row * H_DIM + col]);
            }
        }
}

__global__ __launch_bounds__(256, 2) void k_fused(const float* __restrict__ x,
                                                  const float* __restrict__ h_prev,
                                                  const float* __restrict__ W_u,
                                                  const float* __restrict__ b_u,
                                                  const float* __restrict__ W_hx,
                                                  const float* __restrict__ W_hh,
                                                  const float* __restrict__ b_h,
                                                  const unsigned short* __restrict__ rh,
                                                  float* __restrict__ out) {
    __shared__ unsigned short As[128 * LDSS];
    __shared__ unsigned short Bs[128 * LDSS];
    int bid = blockIdx.x;
    int swz = (bid & 7) * 128 + (bid >> 3);
    int bm = swz >> 3, bn = swz & 7;
    int tid = threadIdx.x;
    int wave = tid >> 6, lane = tid & 63;
    int wm = wave >> 1, wn = wave & 1;
    int frow = lane & 15, koff = (lane >> 4) * 8;
    f32x4 accu[4][4] = {};
    f32x4 accc[4][4] = {};
    for (int ks = 0; ks < H_DIM; ks += 32) {
        stage_f32(h_prev, bm * 128, H_DIM, ks, As, tid);
        stage_f32(W_u, bn * 128, H_DIM, ks, Bs, tid);
        __syncthreads();
        bf16x8 av[4], bv[4];
#pragma unroll
        for (int m = 0; m < 4; ++m)
            av[m] = *reinterpret_cast<const bf16x8*>(&As[(wm * 64 + m * 16 + frow) * LDSS + koff]);
#pragma unroll
        for (int n = 0; n < 4; ++n)
            bv[n] = *reinterpret_cast<const bf16x8*>(&Bs[(wn * 64 + n * 16 + frow) * LDSS + koff]);
#pragma unroll
        for (int m = 0; m < 4; ++m)
#pragma unroll
            for (int n = 0; n < 4; ++n)
                accu[m][n] = __builtin_amdgcn_mfma_f32_16x16x32_bf16(av[m], bv[n], accu[m][n], 0, 0, 0);
        __syncthreads();
    }
    for (int ks = 0; ks < IN_DIM; ks += 32) {
        stage_f32(x, bm * 128, IN_DIM, ks, As, tid);
        stage_f32(W_hx, bn * 128, IN_DIM, ks, Bs, tid);
        __syncthreads();
        bf16x8 av[4], bv[4];
#pragma unroll
        for (int m = 0; m < 4; ++m)
            av[m] = *reinterpret_cast<const bf16x8*>(&As[(wm * 64 + m * 16 + frow) * LDSS + koff]);
#pragma unroll
        for (int n = 0; n < 4; ++n)
            bv[n] = *reinterpret_cast<const bf16x8*>(&Bs[(wn * 64 + n * 16 + frow) * LDSS + koff]);
#pragma unroll
        for (int m = 0; m < 4; ++m)
#pragma unroll
            for (int n = 0; n < 4; ++n)
                accc[m][n] = __builtin_amdgcn_mfma_f32_16x16x32_bf16(av[m], bv[n], accc[m][n], 0, 0, 0);
        __syncthreads();
    }
    for (int ks = 0; ks < H_DIM; ks += 32) {
        stage_bf16s(rh, bm * 128, H_DIM, ks, As, tid);
        stage_f32(W_hh, bn * 128, H_DIM, ks, Bs, tid);
        __syncthreads();
        bf16x8 av[4], bv[4];
#pragma unroll
        for (int m = 0; m < 4; ++m)
            av[m] = *reinterpret_cast<const bf16x8*>(&As[(wm * 64 + m * 16 + frow) * LDSS + koff]);
#pragma unroll
        for (int n = 0; n < 4; ++n)
            bv[n] = *reinterpret_cast<const bf16x8*>(&Bs[(wn * 64 + n * 16 + frow) * LDSS + koff]);
#pragma unroll
        for (int m = 0; m < 4; ++m)
#pragma unroll
            for (int n = 0; n < 4; ++n)
                accc[m][n] = __builtin_amdgcn_mfma_f32_16x16x32_bf16(av[m], bv[n], accc[m][n], 0, 0, 0);
        __syncthreads();
    }
    int rbase = bm * 128 + wm * 64, cbase = bn * 128 + wn * 64;
#pragma unroll
    for (int m = 0; m < 4; ++m)
#pragma unroll
        for (int n = 0; n < 4; ++n) {
            int col = cbase + n * 16 + frow;
            float bu = b_u[col], bh = b_h[col];
#pragma unroll
            for (int q = 0; q < 4; ++q) {
                int row = rbase + m * 16 + (lane >> 4) * 4 + q;
                size_t off = (size_t)row * H_DIM + col;
                float hp = h_prev[off];
                float u = 1.0f / (1.0f + __expf(-(accu[m][n][q] + bu)));
                float cpre = accc[m][n][q] + bh;
                cpre = fminf(fmaxf(cpre, -15.0f), 15.0f);
                float e = __expf(2.0f * cpre);
                float c = (e - 1.0f) / (e + 1.0f);
                float h = hp + u * (c - hp);
                out[off] = h;
                out[BH + off] = h;
            }
        }
}

extern "C" void kernel_launch(void* const* d_in, const int* in_sizes, int n_in,
                              void* d_out, int out_size, void* d_ws, size_t ws_size,
                              hipStream_t stream) {
    const float* x      = (const float*)d_in[0];
    const float* h_prev = (const float*)d_in[1];
    const float* W_u    = (const float*)d_in[2];
    const float* b_u    = (const float*)d_in[3];
    const float* W_r    = (const float*)d_in[4];
    const float* b_r    = (const float*)d_in[5];
    const float* W_hx   = (const float*)d_in[6];
    const float* W_hh   = (const float*)d_in[7];
    const float* b_h    = (const float*)d_in[8];
    float* out = (float*)d_out;

    if (ws_size >= WS2_NEED_BYTES) {
        unsigned short* ws = (unsigned short*)d_ws;
        hipLaunchKernelGGL(k_conv, dim3(2048), dim3(256), 0, stream,
                           x, h_prev, W_u, W_hx, W_hh, W_r, ws);
        hipLaunchKernelGGL(k_rgate_s, dim3(1024), dim3(256), 0, stream,
                           ws + OFF_HB, ws + OFF_WR, b_r, ws + OFF_A2 + 512);
        hipLaunchKernelGGL(k_ugate_s, dim3(1024), dim3(256), 0, stream,
                           ws + OFF_HB, ws + OFF_WU, b_u, ws + OFF_U16);
        hipLaunchKernelGGL(k_cand_b, dim3(1024), dim3(256), 0, stream,
                           ws + OFF_A2, ws + OFF_W2, ws + OFF_HB, ws + OFF_U16,
                           b_h, out);
    } else {
        unsigned short* rh = (unsigned short*)d_ws;
        hipLaunchKernelGGL(k_rgate, dim3(1024), dim3(256), 0, stream, h_prev, W_r, b_r, rh);
        hipLaunchKernelGGL(k_fused, dim3(1024), dim3(256), 0, stream,
                           x, h_prev, W_u, b_u, W_hx, W_hh, b_h, rh, out);
    }
}